// Round 4
// baseline (623.937 us; speedup 1.0000x reference)
//
#include <hip/hip_runtime.h>

// 2x half-pixel bilinear upsample, (16,128,128,128) f32 NHWC -> (16,256,256,128).
// Sliding-window version: each thread owns TJ=4 consecutive input pixels along W
// (fixed b,i,c4), loads each input column once, H-lerps it into 2 registers
// (top/bottom), and slides L/C/R registers along W. Per thread:
// 18 loads (3 rows x 6 columns) -> 16 output float4 stores.
//
// Closed-form weights (FACTOR=2 half-pixel):
//   out[2k]   = 0.25*in[k-1] + 0.75*in[k]   (lo clamped at 0)
//   out[2k+1] = 0.75*in[k]   + 0.25*in[k+1] (hi clamped at n-1)
// Clamped edges: lo==hi -> blend of identical values == the value, matching
// the reference's frac=0 convention.

#define B_  16
#define H_  128
#define W_  128
#define C4_ 32    // 128 channels / 4 per float4
#define HO_ 256
#define WO_ 256
#define TJ  4     // input pixels per thread along W

typedef float f4 __attribute__((ext_vector_type(4)));

// tid bit layout: [b:4][i:7][jg:5][c4:5] -> 2,097,152 threads (8192 blocks x 256)

__global__ __launch_bounds__(256) void upsample2x_slide_kernel(
    const float* __restrict__ in, float* __restrict__ out)
{
    const int tid = blockIdx.x * blockDim.x + threadIdx.x;

    const int c4 = tid & 31;
    const int jg = (tid >> 5) & 31;
    const int i  = (tid >> 10) & 127;
    const int b  = tid >> 17;

    const int j0 = jg * TJ;

    const int im = max(i - 1, 0), ip = min(i + 1, H_ - 1);

    const f4* __restrict__ in4 = reinterpret_cast<const f4*>(in);
    f4* __restrict__ out4 = reinterpret_cast<f4*>(out);

    const int base = b * (H_ * W_ * C4_);
    const int rm = base + im * (W_ * C4_);
    const int r0 = base + i  * (W_ * C4_);
    const int rp = base + ip * (W_ * C4_);

    // Load one input column (3 rows) and H-lerp into top/bottom values.
    auto loadcol = [&](int j, f4& t, f4& bo) {
        const int c = j * C4_ + c4;
        f4 am = in4[rm + c];
        f4 a0 = in4[r0 + c];
        f4 ap = in4[rp + c];
        t  = 0.25f * am + 0.75f * a0;   // output row 2i
        bo = 0.75f * a0 + 0.25f * ap;   // output row 2i+1
    };

    f4 tL, bL, tC, bC, tR, bR;
    loadcol(max(j0 - 1, 0), tL, bL);
    loadcol(j0, tC, bC);

    const int ob  = b * (HO_ * WO_ * C4_);
    const int orT = ob + (2 * i) * (WO_ * C4_);
    const int orB = orT + (WO_ * C4_);

    #pragma unroll
    for (int t = 0; t < TJ; ++t) {
        const int j = j0 + t;
        loadcol(min(j + 1, W_ - 1), tR, bR);

        f4 oTL = 0.25f * tL + 0.75f * tC;   // (2i,   2j)
        f4 oTR = 0.75f * tC + 0.25f * tR;   // (2i,   2j+1)
        f4 oBL = 0.25f * bL + 0.75f * bC;   // (2i+1, 2j)
        f4 oBR = 0.75f * bC + 0.25f * bR;   // (2i+1, 2j+1)

        const int oc = (2 * j) * C4_ + c4;
        out4[orT + oc]        = oTL;
        out4[orT + oc + C4_]  = oTR;
        out4[orB + oc]        = oBL;
        out4[orB + oc + C4_]  = oBR;

        tL = tC; bL = bC; tC = tR; bC = bR;
    }
}

extern "C" void kernel_launch(void* const* d_in, const int* in_sizes, int n_in,
                              void* d_out, int out_size, void* d_ws, size_t ws_size,
                              hipStream_t stream)
{
    const float* in = reinterpret_cast<const float*>(d_in[0]);
    float* out = reinterpret_cast<float*>(d_out);

    const int total = B_ * H_ * (W_ / TJ) * C4_;   // 2,097,152 threads
    const int block = 256;
    const int grid = total / block;                 // 8192 blocks

    upsample2x_slide_kernel<<<grid, block, 0, stream>>>(in, out);
}